// Round 1
// baseline (5740.659 us; speedup 1.0000x reference)
//
#include <hip/hip_runtime.h>
#include <hip/hip_bf16.h>
#include <cstddef>

// ---------------- problem constants ----------------
#define BB    32
#define T1    129
#define TT    128
#define SS    256
#define EE    512
#define HH    1024
#define KK    128
#define VV    128
#define VOC   8000
#define VOCP  8064          // padded to multiple of 128
#define K1    1664          // E + V + H   (LSTM1 combined input)
#define K2    2048          // H + H       (LSTM2 combined input)
#define KLOG  1152          // H + V

typedef __bf16 bf16x8 __attribute__((ext_vector_type(8)));
typedef float  f32x4  __attribute__((ext_vector_type(4)));

// ---------------- weight packing ----------------
// Packed layout: Wp[rp][k], rp = 4*j + gate, orig row = gate*1024 + j.
__global__ void pack_lstm_w(const float* __restrict__ Wih, const float* __restrict__ Whh,
                            __hip_bfloat16* __restrict__ Wp, int Kih, int Ktot)
{
    int rp = blockIdx.y;
    int k  = blockIdx.x * 256 + threadIdx.x;
    if (k >= Ktot) return;
    int j = rp >> 2, g = rp & 3;
    int orow = g * HH + j;
    float w = (k < Kih) ? Wih[(size_t)orow * Kih + k]
                        : Whh[(size_t)orow * HH + (k - Kih)];
    Wp[(size_t)rp * Ktot + k] = __float2bfloat16(w);
}

__global__ void pack_wout(const float* __restrict__ W, __hip_bfloat16* __restrict__ Wp)
{
    int v = blockIdx.y;                 // 0..VOCP-1
    int k = blockIdx.x * 256 + threadIdx.x;
    if (k >= KLOG) return;
    float w = (v < VOC) ? W[(size_t)v * KLOG + k] : 0.f;
    Wp[(size_t)v * KLOG + k] = __float2bfloat16(w);
}

__global__ void pack_bias(const float* __restrict__ b1, const float* __restrict__ b2,
                          float* __restrict__ bp1, float* __restrict__ bp2)
{
    int rp = blockIdx.x * 256 + threadIdx.x;
    if (rp >= 4 * HH) return;
    int j = rp >> 2, g = rp & 3;
    bp1[rp] = b1[g * HH + j];
    bp2[rp] = b2[g * HH + j];
}

// ---------------- init ----------------
__global__ void init_state(const float* __restrict__ enc,
                           float* __restrict__ c1, float* __restrict__ c2,
                           float* __restrict__ h2f,
                           __hip_bfloat16* __restrict__ A1,   // step-0 buffer
                           __hip_bfloat16* __restrict__ A2)   // parity-0 buffer
{
    int i = blockIdx.x * 256 + threadIdx.x;      // 0 .. 32*1024-1
    if (i >= BB * HH) return;
    int b = i >> 10, j = i & 1023;
    c1[i] = 0.f; c2[i] = 0.f;
    float e = enc[i];
    h2f[i] = e;
    __hip_bfloat16 eb = __float2bfloat16(e);
    A2[(size_t)b * K2 + HH + j]        = eb;     // h2(-1) section
    A1[(size_t)b * K1 + (EE + VV) + j] = eb;     // h1(-1) section of step 0
    if (j < VV) A1[(size_t)b * K1 + EE + j] = __float2bfloat16(0.f);  // ctx(-1)=0
}

__global__ void gather_emb(const int* __restrict__ tok, const float* __restrict__ emb,
                           __hip_bfloat16* __restrict__ A1)
{
    int bid = blockIdx.x;          // t*32 + b
    int t = bid >> 5, b = bid & 31;
    int id = tok[b * T1 + t];
    const float* er = emb + (size_t)id * EE;
    __hip_bfloat16* dst = A1 + (size_t)t * BB * K1 + (size_t)b * K1;
    for (int k = threadIdx.x; k < EE; k += 256)
        dst[k] = __float2bfloat16(er[k]);
}

// ---------------- LSTM step (gates GEMM + cell update) ----------------
// grid: 256 blocks (16 packed cols = 4 hidden units each), 256 threads (4 waves).
// Wave w handles k-quarter w.  A is [32][K] bf16 row-major, W packed [4096][K].
template<int K>
__global__ __launch_bounds__(256) void lstm_step(
    const __hip_bfloat16* __restrict__ Ain,
    const __hip_bfloat16* __restrict__ Wp,
    const float* __restrict__ bp,
    float* __restrict__ c,
    __hip_bfloat16* __restrict__ d1, int ld1, int o1,
    __hip_bfloat16* __restrict__ d2, int ld2, int o2,
    float* __restrict__ fdst)
{
    constexpr int KQ = K / 4;
    int n0  = blockIdx.x * 16;               // packed col base
    int wv  = threadIdx.x >> 6;              // k-quarter
    int l   = threadIdx.x & 63;
    int l15 = l & 15, l4 = l >> 4;

    f32x4 acc0 = {0.f,0.f,0.f,0.f}, acc1 = {0.f,0.f,0.f,0.f};
    const __hip_bfloat16* Bp  = Wp  + (size_t)(n0 + l15) * K + wv * KQ + l4 * 8;
    const __hip_bfloat16* Ap0 = Ain + (size_t)l15 * K        + wv * KQ + l4 * 8;
    const __hip_bfloat16* Ap1 = Ap0 + (size_t)16 * K;

    #pragma unroll
    for (int kt = 0; kt < KQ; kt += 32) {
        bf16x8 a0 = *(const bf16x8*)(Ap0 + kt);
        bf16x8 a1 = *(const bf16x8*)(Ap1 + kt);
        bf16x8 bb = *(const bf16x8*)(Bp + kt);
        acc0 = __builtin_amdgcn_mfma_f32_16x16x32_bf16(a0, bb, acc0, 0, 0, 0);
        acc1 = __builtin_amdgcn_mfma_f32_16x16x32_bf16(a1, bb, acc1, 0, 0, 0);
    }

    __shared__ float G[4][32][17];
    #pragma unroll
    for (int r = 0; r < 4; ++r) {
        G[wv][l4 * 4 + r][l15]      = acc0[r];
        G[wv][16 + l4 * 4 + r][l15] = acc1[r];
    }
    __syncthreads();

    if (threadIdx.x < 128) {
        int b = threadIdx.x & 31, jl = threadIdx.x >> 5;      // jl 0..3
        float gi = G[0][b][4*jl+0] + G[1][b][4*jl+0] + G[2][b][4*jl+0] + G[3][b][4*jl+0] + bp[n0 + 4*jl + 0];
        float gf = G[0][b][4*jl+1] + G[1][b][4*jl+1] + G[2][b][4*jl+1] + G[3][b][4*jl+1] + bp[n0 + 4*jl + 1];
        float gg = G[0][b][4*jl+2] + G[1][b][4*jl+2] + G[2][b][4*jl+2] + G[3][b][4*jl+2] + bp[n0 + 4*jl + 2];
        float go = G[0][b][4*jl+3] + G[1][b][4*jl+3] + G[2][b][4*jl+3] + G[3][b][4*jl+3] + bp[n0 + 4*jl + 3];
        int j = (n0 >> 2) + jl;                               // global hidden unit
        float cold = c[b * HH + j];
        float si = 1.f / (1.f + __expf(-gi));
        float sf = 1.f / (1.f + __expf(-gf));
        float so = 1.f / (1.f + __expf(-go));
        float cn = sf * cold + si * tanhf(gg);
        float h  = so * tanhf(cn);
        c[b * HH + j] = cn;
        __hip_bfloat16 hb = __float2bfloat16(h);
        if (d1)   d1[(size_t)b * ld1 + o1 + j] = hb;
        if (d2)   d2[(size_t)b * ld2 + o2 + j] = hb;
        if (fdst) fdst[b * HH + j] = h;
    }
}

// ---------------- attention ----------------
__global__ __launch_bounds__(256) void attn_step(
    const float* __restrict__ h2f, const float* __restrict__ keys,
    const float* __restrict__ vals, const float* __restrict__ Wq,
    const float* __restrict__ bq,
    __hip_bfloat16* __restrict__ d1,       // A1[t+1] ctx section (nullable)
    __hip_bfloat16* __restrict__ dlog)     // Alog + t*32*1152
{
    int b = blockIdx.x;
    __shared__ float hs[HH];
    __shared__ float qs[KK];
    __shared__ float es[SS];
    __shared__ float red[256];

    for (int i = threadIdx.x; i < HH; i += 256) hs[i] = h2f[b * HH + i];
    __syncthreads();

    { // q = h2 @ Wq.T + bq   (2 threads per k, halves of the 1024-dot)
        int k = threadIdx.x & 127, hf = threadIdx.x >> 7;
        const float* wr = Wq + (size_t)k * HH + hf * 512;
        const float* hh = hs + hf * 512;
        float acc = 0.f;
        for (int j = 0; j < 512; j += 4) {
            acc += wr[j]   * hh[j]   + wr[j+1] * hh[j+1]
                 + wr[j+2] * hh[j+2] + wr[j+3] * hh[j+3];
        }
        red[threadIdx.x] = acc;
    }
    __syncthreads();
    if (threadIdx.x < KK) qs[threadIdx.x] = red[threadIdx.x] + red[threadIdx.x + 128] + bq[threadIdx.x];
    __syncthreads();

    { // energy[s] = keys[b,s,:] . q
        int s = threadIdx.x;
        const float4* kr = (const float4*)(keys + ((size_t)b * SS + s) * KK);
        float acc = 0.f;
        for (int k4 = 0; k4 < KK / 4; ++k4) {
            float4 kv = kr[k4];
            acc += kv.x * qs[k4*4] + kv.y * qs[k4*4+1] + kv.z * qs[k4*4+2] + kv.w * qs[k4*4+3];
        }
        es[s] = acc;
    }
    __syncthreads();

    // softmax over 256
    red[threadIdx.x] = es[threadIdx.x];
    __syncthreads();
    for (int off = 128; off > 0; off >>= 1) {
        if (threadIdx.x < off) red[threadIdx.x] = fmaxf(red[threadIdx.x], red[threadIdx.x + off]);
        __syncthreads();
    }
    float mx = red[0];
    __syncthreads();
    float ev = __expf(es[threadIdx.x] - mx);
    es[threadIdx.x] = ev;
    red[threadIdx.x] = ev;
    __syncthreads();
    for (int off = 128; off > 0; off >>= 1) {
        if (threadIdx.x < off) red[threadIdx.x] += red[threadIdx.x + off];
        __syncthreads();
    }
    float inv = 1.f / red[0];
    __syncthreads();

    { // context[v] = sum_s attn[s] * vals[b,s,v]   (2 threads per v, s-halves)
        int v = threadIdx.x & 127, hf = threadIdx.x >> 7;
        const float* vb = vals + ((size_t)b * SS + hf * 128) * VV;
        float acc = 0.f;
        for (int s = 0; s < 128; ++s) acc += es[hf * 128 + s] * vb[(size_t)s * VV + v];
        red[threadIdx.x] = acc;
    }
    __syncthreads();
    if (threadIdx.x < VV) {
        float cv = (red[threadIdx.x] + red[threadIdx.x + 128]) * inv;
        __hip_bfloat16 cb = __float2bfloat16(cv);
        if (d1) d1[(size_t)blockIdx.x * K1 + EE + threadIdx.x] = cb;
        dlog[(size_t)blockIdx.x * KLOG + HH + threadIdx.x] = cb;
    }
}

// ---------------- deferred logits GEMM ----------------
// out[b][t][v] = Alog[m=t*32+b] . Wout[v] + bout[v];  tile 128M x 128N
__global__ __launch_bounds__(256) void logits_gemm(
    const __hip_bfloat16* __restrict__ Alog,
    const __hip_bfloat16* __restrict__ W,
    const float* __restrict__ bout,
    float* __restrict__ out)
{
    int n0 = blockIdx.x * 128;
    int m0 = blockIdx.y * 128;
    int wv = threadIdx.x >> 6, l = threadIdx.x & 63;
    int l15 = l & 15, l4 = l >> 4;

    f32x4 acc[8][2] = {};
    const __hip_bfloat16* Ap = Alog + (size_t)(m0 + l15) * KLOG + l4 * 8;
    const __hip_bfloat16* Bp = W    + (size_t)(n0 + wv * 32 + l15) * KLOG + l4 * 8;

    for (int kt = 0; kt < KLOG; kt += 32) {
        bf16x8 b0 = *(const bf16x8*)(Bp + kt);
        bf16x8 b1 = *(const bf16x8*)(Bp + (size_t)16 * KLOG + kt);
        #pragma unroll
        for (int ms = 0; ms < 8; ++ms) {
            bf16x8 a = *(const bf16x8*)(Ap + (size_t)ms * 16 * KLOG + kt);
            acc[ms][0] = __builtin_amdgcn_mfma_f32_16x16x32_bf16(a, b0, acc[ms][0], 0, 0, 0);
            acc[ms][1] = __builtin_amdgcn_mfma_f32_16x16x32_bf16(a, b1, acc[ms][1], 0, 0, 0);
        }
    }

    #pragma unroll
    for (int ms = 0; ms < 8; ++ms) {
        #pragma unroll
        for (int ns = 0; ns < 2; ++ns) {
            int col = n0 + wv * 32 + ns * 16 + l15;
            if (col < VOC) {
                float bias = bout[col];
                #pragma unroll
                for (int r = 0; r < 4; ++r) {
                    int m = m0 + ms * 16 + l4 * 4 + r;
                    int b = m & 31, t = m >> 5;
                    out[((size_t)b * TT + t) * VOC + col] = acc[ms][ns][r] + bias;
                }
            }
        }
    }
}

// ---------------- host ----------------
extern "C" void kernel_launch(void* const* d_in, const int* in_sizes, int n_in,
                              void* d_out, int out_size, void* d_ws, size_t ws_size,
                              hipStream_t stream)
{
    const int*   dec  = (const int*)  d_in[0];
    const float* enc  = (const float*)d_in[2];
    const float* keys = (const float*)d_in[3];
    const float* vals = (const float*)d_in[4];
    const float* emb  = (const float*)d_in[5];
    const float* Wih1 = (const float*)d_in[6];
    const float* Whh1 = (const float*)d_in[7];
    const float* b1   = (const float*)d_in[8];
    const float* Wih2 = (const float*)d_in[9];
    const float* Whh2 = (const float*)d_in[10];
    const float* b2   = (const float*)d_in[11];
    const float* Wq   = (const float*)d_in[12];
    const float* bq   = (const float*)d_in[13];
    const float* Wout = (const float*)d_in[14];
    const float* bout = (const float*)d_in[15];
    float* out = (float*)d_out;

    // workspace carve (all sizes multiples of 256B)
    char* p = (char*)d_ws;
    __hip_bfloat16* Wp1   = (__hip_bfloat16*)p; p += (size_t)4*HH * K1 * 2;        // 13.6 MB
    __hip_bfloat16* Wp2   = (__hip_bfloat16*)p; p += (size_t)4*HH * K2 * 2;        // 16.8 MB
    __hip_bfloat16* WoutP = (__hip_bfloat16*)p; p += (size_t)VOCP * KLOG * 2;      // 18.6 MB
    __hip_bfloat16* A1    = (__hip_bfloat16*)p; p += (size_t)TT * BB * K1 * 2;     // 13.6 MB
    __hip_bfloat16* A2    = (__hip_bfloat16*)p; p += (size_t)2 * BB * K2 * 2;      // 256 KB
    __hip_bfloat16* Alog  = (__hip_bfloat16*)p; p += (size_t)TT * BB * KLOG * 2;   // 9.4 MB
    float* bp1 = (float*)p; p += (size_t)4*HH*4;
    float* bp2 = (float*)p; p += (size_t)4*HH*4;
    float* c1  = (float*)p; p += (size_t)BB*HH*4;
    float* c2  = (float*)p; p += (size_t)BB*HH*4;
    float* h2f = (float*)p; p += (size_t)BB*HH*4;

    // pack weights / biases (every call; deterministic)
    pack_lstm_w<<<dim3((K1+255)/256, 4*HH), 256, 0, stream>>>(Wih1, Whh1, Wp1, EE+VV, K1);
    pack_lstm_w<<<dim3((K2+255)/256, 4*HH), 256, 0, stream>>>(Wih2, Whh2, Wp2, HH,    K2);
    pack_wout  <<<dim3((KLOG+255)/256, VOCP), 256, 0, stream>>>(Wout, WoutP);
    pack_bias  <<<dim3(16), 256, 0, stream>>>(b1, b2, bp1, bp2);
    init_state <<<dim3(128), 256, 0, stream>>>(enc, c1, c2, h2f, A1, A2);
    gather_emb <<<dim3(TT*BB), 256, 0, stream>>>(dec, emb, A1);

    const size_t a1s = (size_t)BB * K1;     // per-step A1 stride (elements)
    const size_t a2s = (size_t)BB * K2;
    for (int t = 0; t < TT; ++t) {
        __hip_bfloat16* A1next = (t < TT-1) ? A1 + (size_t)(t+1) * a1s : nullptr;
        // LSTM layer 1: A = [emb | ctx | h1prev]
        lstm_step<K1><<<dim3(256), 256, 0, stream>>>(
            A1 + (size_t)t * a1s, Wp1, bp1, c1,
            A1next, K1, EE + VV,                 // h1 -> next step's A1
            A2 + (size_t)(t & 1) * a2s, K2, 0,   // h1 -> this step's A2
            nullptr);
        // LSTM layer 2: A = [h1 | h2prev]
        lstm_step<K2><<<dim3(256), 256, 0, stream>>>(
            A2 + (size_t)(t & 1) * a2s, Wp2, bp2, c2,
            A2 + (size_t)((t + 1) & 1) * a2s, K2, HH,   // h2 -> next parity buffer
            Alog + (size_t)t * BB * KLOG, KLOG, 0,      // h2 -> logits A-store
            h2f);
        // attention -> context
        attn_step<<<dim3(BB), 256, 0, stream>>>(
            h2f, keys, vals, Wq, bq,
            A1next,                                    // ctx -> next step's A1
            Alog + (size_t)t * BB * KLOG);
    }

    logits_gemm<<<dim3(VOCP/128, (BB*TT)/128), 256, 0, stream>>>(Alog, WoutP, bout, out);
}